// Round 4
// baseline (166.595 us; speedup 1.0000x reference)
//
#include <hip/hip_runtime.h>
#include <hip/hip_bf16.h>
#include <math.h>

// FFM: B=32768, n=512, f=30, k=40
// inter[b] = X[b]^T W X[b],  W = 0.5*(C - diag(C)), C symmetric
// out = sigmoid(X@w1 + b + inter)
//
// R9: 32x32x16 MFMA (2x FLOP per operand byte vs 16x16x32), 64x64 tile per
// wave, 8 waves cover 64 rows x all 512 cols per K-step -> single
// accumulation, single epilogue. BK=32, 16 steps, Bs dbuf 2x32KB staged via
// counted-vmcnt global_load_lds. kc-major chunk layouts for As/Bs: fragment
// reads are contiguous-per-half-wave -> conflict-free (As writes XOR-swz).
// Epilogue x read from global f32 X (L2-hot, coalesced). launch_bounds(512,1)
// -> 256-VGPR cap (R8 lesson: 2nd arg acts as blocks/CU; (512,2) capped 128
// and spilled 22.6MB/dispatch).

#define N_FEAT 512
#define FK 1200
#define KDIM 40
#define B_ROWS 32768
#define BM 64
#define BKS 32
#define NSTEP 16

typedef __attribute__((ext_vector_type(8))) short short8;
typedef __attribute__((ext_vector_type(16))) float f32x16;

__device__ __forceinline__ unsigned short bf16_rne(float f) {
    union { float f; unsigned int u; } c; c.f = f;
    unsigned int u = c.u;
    u += 0x7fffu + ((u >> 16) & 1u);
    return (unsigned short)(u >> 16);
}

__device__ __forceinline__ void async_copy16(const void* g, void* l) {
    __builtin_amdgcn_global_load_lds(
        (const __attribute__((address_space(1))) void*)g,
        (__attribute__((address_space(3))) void*)l,
        16, 0, 0);
}

#define FENCE() asm volatile("" ::: "memory")

// ---------------- Kernel 1: build W16 (512x512 bf16) ----------------
__global__ __launch_bounds__(256) void build_w16(const float* __restrict__ v,
                                                 const int* __restrict__ f2f,
                                                 unsigned short* __restrict__ W16) {
    __shared__ float a_lds[FK];          // 4.8 KB
    __shared__ float c_lds[256 * 44];    // 45 KB (pad 40->44)

    const int i   = blockIdx.y;
    const int j0  = blockIdx.x * 256;
    const int tid = threadIdx.x;
    const int fi  = f2f[i];

    for (int q = tid; q < FK; q += 256) a_lds[q] = v[(size_t)i * FK + q];
    for (int q = tid; q < 2560; q += 256) {
        const int jl = q / 10, c4 = q % 10;
        *(float4*)&c_lds[jl * 44 + c4 * 4] =
            *(const float4*)&v[(size_t)(j0 + jl) * FK + fi * KDIM + c4 * 4];
    }
    __syncthreads();

    const int j  = j0 + tid;
    const int fj = f2f[j];
    const float4* a = (const float4*)&a_lds[fj * KDIM];
    const float4* c = (const float4*)&c_lds[tid * 44];
    float acc = 0.f;
#pragma unroll
    for (int q = 0; q < KDIM / 4; ++q) {
        float4 av = a[q], cv = c[q];
        acc = fmaf(av.x, cv.x, acc);
        acc = fmaf(av.y, cv.y, acc);
        acc = fmaf(av.z, cv.z, acc);
        acc = fmaf(av.w, cv.w, acc);
    }
    W16[(size_t)i * N_FEAT + j] = (i == j) ? (unsigned short)0 : bf16_rne(0.5f * acc);
}

// ---------------- Kernel 2: fused GEMM + quadratic-form epilogue ----------------
// grid: 512 blocks x 512 threads (8 waves). Wave w owns output cols
// [w*64, w*64+64) for all 64 rows (2x2 of 32x32 frags, acc = 64 VGPR).
// As: kc-major 16B chunks, chunk(kc,r) at index kc*64 + (r^(kc&7)).
// Bs: kc-major, chunk(kcl,col) at index kcl*512 + col (conflict-free).
__global__ __launch_bounds__(512, 1) void ffm_fused(const float* __restrict__ X,
                                                    const unsigned short* __restrict__ W16,
                                                    const float* __restrict__ w1,
                                                    const float* __restrict__ bvec,
                                                    float* __restrict__ out) {
    __shared__ __align__(16) unsigned short As[BM * N_FEAT];      // 64 KB
    __shared__ __align__(16) unsigned short Bs[2][N_FEAT * BKS];  // 2 x 32 KB
    __shared__ float part[8 * BM];                                // 2 KB

    const int tid  = threadIdx.x;
    const int lane = tid & 63;
    const int wave = tid >> 6;      // 0..7
    const int half = lane >> 5;     // 0/1
    const int l31  = lane & 31;

    const size_t row0 = (size_t)blockIdx.x * BM;

    // B staging: lane's W16 row = output col (W symmetric: W16[col][k] = B[k][col]).
    const unsigned short* wrow = W16 + (size_t)(wave * 64 + lane) * N_FEAT;

    // Stage step-s tile (512 cols x 32 k) into Bs[s&1]: 4 async 16B per thread.
    // Instr i covers chunks [i*512 + wave*64, +64): dest wave-uniform, lane adds 16B.
    auto stage = [&](int s) {
        unsigned short* dst = (unsigned short*)Bs[s & 1];
#pragma unroll
        for (int i = 0; i < 4; ++i)
            async_copy16(wrow + s * BKS + i * 8, dst + (i * 512 + wave * 64) * 8);
    };

    // ---- Prologue: issue tile-0 staging, build As under it ----
    stage(0);
    {
        const float4* X4 = (const float4*)(X + row0 * N_FEAT);
#pragma unroll
        for (int u = 0; u < 8; ++u) {
            const int g  = u * 512 + tid;
            const int r  = g >> 6;      // wave-uniform row 0..63
            const int kc = g & 63;      // = lane: 16B chunk in row
            float4 f0 = X4[r * 128 + kc * 2];
            float4 f1 = X4[r * 128 + kc * 2 + 1];
            union { unsigned short us[8]; short8 v; } pk;
            pk.us[0] = bf16_rne(f0.x);
            pk.us[1] = bf16_rne(f0.y);
            pk.us[2] = bf16_rne(f0.z);
            pk.us[3] = bf16_rne(f0.w);
            pk.us[4] = bf16_rne(f1.x);
            pk.us[5] = bf16_rne(f1.y);
            pk.us[6] = bf16_rne(f1.z);
            pk.us[7] = bf16_rne(f1.w);
            *(short8*)(As + ((size_t)kc * 64 + (r ^ (kc & 7))) * 8) = pk.v;
        }
    }
    asm volatile("s_waitcnt lgkmcnt(0)" ::: "memory");
    __builtin_amdgcn_s_barrier();
    FENCE();

    f32x16 acc[2][2];
#pragma unroll
    for (int mi = 0; mi < 2; ++mi)
#pragma unroll
        for (int ci = 0; ci < 2; ++ci)
#pragma unroll
            for (int r = 0; r < 16; ++r) acc[mi][ci][r] = 0.f;

#pragma unroll
    for (int t = 0; t < NSTEP; ++t) {
        if (t < NSTEP - 1) {
            stage(t + 1);
            asm volatile("s_waitcnt vmcnt(4)" ::: "memory");  // cur tile done, next in flight
        } else {
            asm volatile("s_waitcnt vmcnt(0)" ::: "memory");
        }
        __builtin_amdgcn_s_barrier();   // all waves' cur-buf loads landed
        FENCE();

        const unsigned short* bs = (const unsigned short*)Bs[t & 1];
        __builtin_amdgcn_s_setprio(1);
#pragma unroll
        for (int si = 0; si < 2; ++si) {
            const int kcg = t * 4 + si * 2 + half;   // global 8-elem k-chunk
            const int ksw = kcg & 7;
            short8 a[2], b[2];
#pragma unroll
            for (int mi = 0; mi < 2; ++mi) {
                const int ar = mi * 32 + l31;        // A row
                a[mi] = *(const short8*)(As + ((size_t)kcg * 64 + (ar ^ ksw)) * 8);
            }
#pragma unroll
            for (int ci = 0; ci < 2; ++ci) {
                const int col = wave * 64 + ci * 32 + l31;
                b[ci] = *(const short8*)(bs + ((size_t)(si * 2 + half) * 512 + col) * 8);
            }
#pragma unroll
            for (int mi = 0; mi < 2; ++mi)
#pragma unroll
                for (int ci = 0; ci < 2; ++ci)
                    acc[mi][ci] = __builtin_amdgcn_mfma_f32_32x32x16_bf16(
                        a[mi], b[ci], acc[mi][ci], 0, 0, 0);
        }
        __builtin_amdgcn_s_setprio(0);
        FENCE();
        __builtin_amdgcn_s_barrier();   // cur-buf reads done before next overwrite
        FENCE();
    }

    // ---- Epilogue: rs[row] = sum_col x[row][col] * (y + w1), x from global f32 X.
    // C/D 32x32 layout: col = l31 (+ci*32+wave*64), row = (reg&3)+8*(reg>>2)+4*half (+mi*32).
    float w1v[2];
#pragma unroll
    for (int ci = 0; ci < 2; ++ci) w1v[ci] = w1[wave * 64 + ci * 32 + l31];
    const float bias = bvec[0];

    float rs[2][16];
#pragma unroll
    for (int mi = 0; mi < 2; ++mi) {
#pragma unroll
        for (int reg = 0; reg < 16; ++reg) {
            const int row = mi * 32 + (reg & 3) + 8 * (reg >> 2) + 4 * half;
            const float* xr = X + (row0 + row) * N_FEAT;
            float s = 0.f;
#pragma unroll
            for (int ci = 0; ci < 2; ++ci) {
                const int col = wave * 64 + ci * 32 + l31;
                s = fmaf(xr[col], acc[mi][ci][reg] + w1v[ci], s);
            }
            rs[mi][reg] = s;
        }
    }

    // Reduce over the 32 cols held across l31, then combine 8 waves via part[].
#pragma unroll
    for (int mi = 0; mi < 2; ++mi)
#pragma unroll
        for (int reg = 0; reg < 16; ++reg) {
            float r = rs[mi][reg];
#pragma unroll
            for (int off = 1; off < 32; off <<= 1)
                r += __shfl_xor(r, off, 32);
            rs[mi][reg] = r;
        }
    if (l31 == 0) {
#pragma unroll
        for (int mi = 0; mi < 2; ++mi)
#pragma unroll
            for (int reg = 0; reg < 16; ++reg) {
                const int row = mi * 32 + (reg & 3) + 8 * (reg >> 2) + 4 * half;
                part[wave * 64 + row] = rs[mi][reg];
            }
    }
    __syncthreads();

    if (tid < BM) {
        float tsum = bias;
#pragma unroll
        for (int w = 0; w < 8; ++w) tsum += part[w * 64 + tid];
        out[row0 + tid] = 1.0f / (1.0f + expf(-tsum));
    }
}

extern "C" void kernel_launch(void* const* d_in, const int* in_sizes, int n_in,
                              void* d_out, int out_size, void* d_ws, size_t ws_size,
                              hipStream_t stream) {
    const float* X   = (const float*)d_in[0];   // 32768 x 512
    const float* w1  = (const float*)d_in[1];   // 512
    const float* b   = (const float*)d_in[2];   // 1
    const float* v   = (const float*)d_in[3];   // 512 x 30 x 40
    const int*   f2f = (const int*)d_in[4];     // 512
    float* out = (float*)d_out;                 // 32768

    unsigned short* W16 = (unsigned short*)d_ws;   // 512 KB scratch

    build_w16<<<dim3(2, N_FEAT), 256, 0, stream>>>(v, f2f, W16);
    ffm_fused<<<B_ROWS / BM, 512, 0, stream>>>(X, W16, w1, b, out);
}

// Round 5
// 137.045 us; speedup vs baseline: 1.2156x; 1.2156x over previous
//
#include <hip/hip_runtime.h>
#include <hip/hip_bf16.h>
#include <math.h>

// FFM: B=32768, n=512, f=30, k=40
// inter[b] = X[b]^T W X[b],  W = 0.5*(C - diag(C)), C symmetric
// out = sigmoid(X@w1 + b + inter)
//
// R10: transpose moved to build time. build_wpk emits the weight matrix in
// chunked "staging order": unit(kc,col) = 16B of W[kc*8..+8][col] at linear
// offset (kc*512+col)*16B == Bs LDS layout. ffm_fused stage() is then a pure
// contiguous memcpy (64 lanes x 16B = 1KB/instr, perfectly coalesced; R9's
// 1024-B-stride scatter was 64 L2 transactions/instr and cost ~4x). Inner
// loop (32x32x16 MFMA, kc-major As/Bs, 0 bank conflicts) unchanged from R9.
// Epilogue x-hat back to As reads (R9's global-X re-read added 15MB HBM).

#define N_FEAT 512
#define FK 1200
#define KDIM 40
#define B_ROWS 32768
#define BM 64
#define BKS 32
#define NSTEP 16

typedef __attribute__((ext_vector_type(8))) short short8;
typedef __attribute__((ext_vector_type(16))) float f32x16;

__device__ __forceinline__ unsigned short bf16_rne(float f) {
    union { float f; unsigned int u; } c; c.f = f;
    unsigned int u = c.u;
    u += 0x7fffu + ((u >> 16) & 1u);
    return (unsigned short)(u >> 16);
}

__device__ __forceinline__ float bf16_to_f(unsigned short h) {
    union { unsigned int u; float f; } c;
    c.u = ((unsigned int)h) << 16;
    return c.f;
}

__device__ __forceinline__ void async_copy16(const void* g, void* l) {
    __builtin_amdgcn_global_load_lds(
        (const __attribute__((address_space(1))) void*)g,
        (__attribute__((address_space(3))) void*)l,
        16, 0, 0);
}

#define FENCE() asm volatile("" ::: "memory")

// ---------------- Kernel 1: build Wpk (512x512 bf16, chunked layout) ----------------
// Thread (i = blockIdx.y, j = blockIdx.x*256+tid) computes C[i][j] and stores
// B[j][i] (symmetry) at chunk unit (j>>3)*512 + i, elem j&7:
//   Wpk_u16[ ((j>>3)*512 + i)*8 + (j&7) ]
// Lanes 0-7 (consecutive j) write one contiguous 16B unit -> merged stores.
__global__ __launch_bounds__(256) void build_wpk(const float* __restrict__ v,
                                                 const int* __restrict__ f2f,
                                                 unsigned short* __restrict__ Wpk) {
    __shared__ float a_lds[FK];          // 4.8 KB
    __shared__ float c_lds[256 * 44];    // 45 KB (pad 40->44)

    const int i   = blockIdx.y;
    const int j0  = blockIdx.x * 256;
    const int tid = threadIdx.x;
    const int fi  = f2f[i];

    for (int q = tid; q < FK; q += 256) a_lds[q] = v[(size_t)i * FK + q];
    for (int q = tid; q < 2560; q += 256) {
        const int jl = q / 10, c4 = q % 10;
        *(float4*)&c_lds[jl * 44 + c4 * 4] =
            *(const float4*)&v[(size_t)(j0 + jl) * FK + fi * KDIM + c4 * 4];
    }
    __syncthreads();

    const int j  = j0 + tid;
    const int fj = f2f[j];
    const float4* a = (const float4*)&a_lds[fj * KDIM];
    const float4* c = (const float4*)&c_lds[tid * 44];
    float acc = 0.f;
#pragma unroll
    for (int q = 0; q < KDIM / 4; ++q) {
        float4 av = a[q], cv = c[q];
        acc = fmaf(av.x, cv.x, acc);
        acc = fmaf(av.y, cv.y, acc);
        acc = fmaf(av.z, cv.z, acc);
        acc = fmaf(av.w, cv.w, acc);
    }
    const unsigned short val = (i == j) ? (unsigned short)0 : bf16_rne(0.5f * acc);
    Wpk[((size_t)(j >> 3) * 512 + i) * 8 + (j & 7)] = val;
}

// ---------------- Kernel 2: fused GEMM + quadratic-form epilogue ----------------
// grid: 512 blocks x 512 threads (8 waves). Wave w owns output cols
// [w*64, w*64+64) for all 64 rows (2x2 of 32x32x16 frags, acc = 64 VGPR).
// As: kc-major 16B chunks, chunk(kc,r) at unit kc*64 + (r^(kc&7)).
// Bs: kc-major, chunk(kcl,col) at unit kcl*512 + col  == Wpk staging order.
__global__ __launch_bounds__(512, 1) void ffm_fused(const float* __restrict__ X,
                                                    const unsigned short* __restrict__ Wpk,
                                                    const float* __restrict__ w1,
                                                    const float* __restrict__ bvec,
                                                    float* __restrict__ out) {
    __shared__ __align__(16) unsigned short As[BM * N_FEAT];      // 64 KB
    __shared__ __align__(16) unsigned short Bs[2][N_FEAT * BKS];  // 2 x 32 KB
    __shared__ float part[8 * BM];                                // 2 KB

    const int tid  = threadIdx.x;
    const int lane = tid & 63;
    const int wave = tid >> 6;      // 0..7
    const int half = lane >> 5;     // 0/1
    const int l31  = lane & 31;

    const size_t row0 = (size_t)blockIdx.x * BM;

    // Stage step-s tile (32 k x 512 cols = 32 KB) into Bs[s&1].
    // Global and LDS offsets are the SAME linear unit index: instr i covers
    // units [i*512 + wave*64, +64) -> 64 lanes x 16B contiguous, dest
    // wave-uniform base + lane*16.
    auto stage = [&](int s) {
        unsigned short* dst = (unsigned short*)Bs[s & 1];
#pragma unroll
        for (int i = 0; i < 4; ++i) {
            const int ul = i * 512 + wave * 64 + lane;                 // unit in tile
            async_copy16(Wpk + ((size_t)s * 2048 + ul) * 8, dst + (size_t)ul * 8);
        }
    };

    // ---- Prologue: issue tile-0 staging, build As under it ----
    stage(0);
    {
        const float4* X4 = (const float4*)(X + row0 * N_FEAT);
#pragma unroll
        for (int u = 0; u < 8; ++u) {
            const int g  = u * 512 + tid;
            const int r  = g >> 6;      // wave-uniform row 0..63
            const int kc = g & 63;      // = lane: 16B chunk in row
            float4 f0 = X4[r * 128 + kc * 2];
            float4 f1 = X4[r * 128 + kc * 2 + 1];
            union { unsigned short us[8]; short8 v; } pk;
            pk.us[0] = bf16_rne(f0.x);
            pk.us[1] = bf16_rne(f0.y);
            pk.us[2] = bf16_rne(f0.z);
            pk.us[3] = bf16_rne(f0.w);
            pk.us[4] = bf16_rne(f1.x);
            pk.us[5] = bf16_rne(f1.y);
            pk.us[6] = bf16_rne(f1.z);
            pk.us[7] = bf16_rne(f1.w);
            *(short8*)(As + ((size_t)kc * 64 + (r ^ (kc & 7))) * 8) = pk.v;
        }
    }
    asm volatile("s_waitcnt lgkmcnt(0)" ::: "memory");
    __builtin_amdgcn_s_barrier();
    FENCE();

    f32x16 acc[2][2];
#pragma unroll
    for (int mi = 0; mi < 2; ++mi)
#pragma unroll
        for (int ci = 0; ci < 2; ++ci)
#pragma unroll
            for (int r = 0; r < 16; ++r) acc[mi][ci][r] = 0.f;

#pragma unroll
    for (int t = 0; t < NSTEP; ++t) {
        if (t < NSTEP - 1) {
            stage(t + 1);
            asm volatile("s_waitcnt vmcnt(4)" ::: "memory");  // cur tile done, next in flight
        } else {
            asm volatile("s_waitcnt vmcnt(0)" ::: "memory");
        }
        __builtin_amdgcn_s_barrier();   // all waves' cur-buf loads landed
        FENCE();

        const unsigned short* bs = (const unsigned short*)Bs[t & 1];
        __builtin_amdgcn_s_setprio(1);
#pragma unroll
        for (int si = 0; si < 2; ++si) {
            const int kcg = t * 4 + si * 2 + half;   // global 8-elem k-chunk
            const int ksw = kcg & 7;
            short8 a[2], b[2];
#pragma unroll
            for (int mi = 0; mi < 2; ++mi) {
                const int ar = mi * 32 + l31;        // A row
                a[mi] = *(const short8*)(As + ((size_t)kcg * 64 + (ar ^ ksw)) * 8);
            }
#pragma unroll
            for (int ci = 0; ci < 2; ++ci) {
                const int col = wave * 64 + ci * 32 + l31;
                b[ci] = *(const short8*)(bs + ((size_t)(si * 2 + half) * 512 + col) * 8);
            }
#pragma unroll
            for (int mi = 0; mi < 2; ++mi)
#pragma unroll
                for (int ci = 0; ci < 2; ++ci)
                    acc[mi][ci] = __builtin_amdgcn_mfma_f32_32x32x16_bf16(
                        a[mi], b[ci], acc[mi][ci], 0, 0, 0);
        }
        __builtin_amdgcn_s_setprio(0);
        FENCE();
        __builtin_amdgcn_s_barrier();   // cur-buf reads done before next overwrite
        FENCE();
    }

    // ---- Epilogue: rs[row] = sum_col x[row][col]*(y + w1), x-hat from As (bf16).
    // C/D 32x32 layout: col = l31 (+ci*32+wave*64), row = (reg&3)+8*(reg>>2)+4*half (+mi*32).
    float w1v[2];
#pragma unroll
    for (int ci = 0; ci < 2; ++ci) w1v[ci] = w1[wave * 64 + ci * 32 + l31];
    const float bias = bvec[0];

    float rs[2][16];
#pragma unroll
    for (int mi = 0; mi < 2; ++mi) {
#pragma unroll
        for (int reg = 0; reg < 16; ++reg) {
            const int row = mi * 32 + (reg & 3) + 8 * (reg >> 2) + 4 * half;
            float s = 0.f;
#pragma unroll
            for (int ci = 0; ci < 2; ++ci) {
                const int gc = wave * 64 + ci * 32 + l31;     // k-index 0..511
                const int kc = gc >> 3;
                const float xf = bf16_to_f(As[((size_t)kc * 64 + (row ^ (kc & 7))) * 8 + (gc & 7)]);
                s = fmaf(xf, acc[mi][ci][reg] + w1v[ci], s);
            }
            rs[mi][reg] = s;
        }
    }

    // Reduce over the 32 cols held across l31, then combine 8 waves via part[].
#pragma unroll
    for (int mi = 0; mi < 2; ++mi)
#pragma unroll
        for (int reg = 0; reg < 16; ++reg) {
            float r = rs[mi][reg];
#pragma unroll
            for (int off = 1; off < 32; off <<= 1)
                r += __shfl_xor(r, off, 32);
            rs[mi][reg] = r;
        }
    if (l31 == 0) {
#pragma unroll
        for (int mi = 0; mi < 2; ++mi)
#pragma unroll
            for (int reg = 0; reg < 16; ++reg) {
                const int row = mi * 32 + (reg & 3) + 8 * (reg >> 2) + 4 * half;
                part[wave * 64 + row] = rs[mi][reg];
            }
    }
    __syncthreads();

    if (tid < BM) {
        float tsum = bias;
#pragma unroll
        for (int w = 0; w < 8; ++w) tsum += part[w * 64 + tid];
        out[row0 + tid] = 1.0f / (1.0f + expf(-tsum));
    }
}

extern "C" void kernel_launch(void* const* d_in, const int* in_sizes, int n_in,
                              void* d_out, int out_size, void* d_ws, size_t ws_size,
                              hipStream_t stream) {
    const float* X   = (const float*)d_in[0];   // 32768 x 512
    const float* w1  = (const float*)d_in[1];   // 512
    const float* b   = (const float*)d_in[2];   // 1
    const float* v   = (const float*)d_in[3];   // 512 x 30 x 40
    const int*   f2f = (const int*)d_in[4];     // 512
    float* out = (float*)d_out;                 // 32768

    unsigned short* Wpk = (unsigned short*)d_ws;   // 512 KB scratch (chunked layout)

    build_wpk<<<dim3(2, N_FEAT), 256, 0, stream>>>(v, f2f, Wpk);
    ffm_fused<<<B_ROWS / BM, 512, 0, stream>>>(X, Wpk, w1, b, out);
}

// Round 6
// 132.141 us; speedup vs baseline: 1.2607x; 1.0371x over previous
//
#include <hip/hip_runtime.h>
#include <hip/hip_bf16.h>
#include <math.h>

// FFM: B=32768, n=512, f=30, k=40
// inter[b] = X[b]^T W X[b],  W = 0.5*(C - diag(C)), C symmetric
// out = sigmoid(X@w1 + b + inter)
//
// R11: barrier-free software-pipelined K-loop. Key insight: with the R10
// layout each wave reads back EXACTLY the Bs units it staged itself
// (stage units i*512+wave*64+lane == b-frag units (si*2+half)*512+wave*64
// +ci*32+l31), so Bs needs no cross-wave sync. K-loop: lgkmcnt(0) ->
// stage(t+2) -> vmcnt(4) -> ds_read frags(t+1) -> MFMA(frags(t)).
// Zero s_barrier in the loop (R5/R7/R10 all stalled ~3x on 2-phase
// barrier lockstep; m233 regime). Frags double-buffered in registers.
// Layouts/MFMA shape unchanged from R10 (0 bank conflicts measured).

#define N_FEAT 512
#define FK 1200
#define KDIM 40
#define B_ROWS 32768
#define BM 64
#define BKS 32
#define NSTEP 16

typedef __attribute__((ext_vector_type(8))) short short8;
typedef __attribute__((ext_vector_type(16))) float f32x16;

__device__ __forceinline__ unsigned short bf16_rne(float f) {
    union { float f; unsigned int u; } c; c.f = f;
    unsigned int u = c.u;
    u += 0x7fffu + ((u >> 16) & 1u);
    return (unsigned short)(u >> 16);
}

__device__ __forceinline__ float bf16_to_f(unsigned short h) {
    union { unsigned int u; float f; } c;
    c.u = ((unsigned int)h) << 16;
    return c.f;
}

__device__ __forceinline__ void async_copy16(const void* g, void* l) {
    __builtin_amdgcn_global_load_lds(
        (const __attribute__((address_space(1))) void*)g,
        (__attribute__((address_space(3))) void*)l,
        16, 0, 0);
}

// ---------------- Kernel 1: build Wpk (512x512 bf16, chunked layout) ----------------
// Thread (i = blockIdx.y, j = blockIdx.x*256+tid) computes C[i][j], stores
// B[j][i] (symmetry) at chunk unit (j>>3)*512 + i, elem j&7. Lanes 0-7
// (consecutive j) write one contiguous 16B unit -> merged stores.
__global__ __launch_bounds__(256) void build_wpk(const float* __restrict__ v,
                                                 const int* __restrict__ f2f,
                                                 unsigned short* __restrict__ Wpk) {
    __shared__ float a_lds[FK];          // 4.8 KB
    __shared__ float c_lds[256 * 44];    // 45 KB (pad 40->44)

    const int i   = blockIdx.y;
    const int j0  = blockIdx.x * 256;
    const int tid = threadIdx.x;
    const int fi  = f2f[i];

    for (int q = tid; q < FK; q += 256) a_lds[q] = v[(size_t)i * FK + q];
    for (int q = tid; q < 2560; q += 256) {
        const int jl = q / 10, c4 = q % 10;
        *(float4*)&c_lds[jl * 44 + c4 * 4] =
            *(const float4*)&v[(size_t)(j0 + jl) * FK + fi * KDIM + c4 * 4];
    }
    __syncthreads();

    const int j  = j0 + tid;
    const int fj = f2f[j];
    const float4* a = (const float4*)&a_lds[fj * KDIM];
    const float4* c = (const float4*)&c_lds[tid * 44];
    float acc = 0.f;
#pragma unroll
    for (int q = 0; q < KDIM / 4; ++q) {
        float4 av = a[q], cv = c[q];
        acc = fmaf(av.x, cv.x, acc);
        acc = fmaf(av.y, cv.y, acc);
        acc = fmaf(av.z, cv.z, acc);
        acc = fmaf(av.w, cv.w, acc);
    }
    const unsigned short val = (i == j) ? (unsigned short)0 : bf16_rne(0.5f * acc);
    Wpk[((size_t)(j >> 3) * 512 + i) * 8 + (j & 7)] = val;
}

// ---------------- Kernel 2: fused GEMM + quadratic-form epilogue ----------------
// grid: 512 blocks x 512 threads (8 waves). Wave w owns output cols
// [w*64, w*64+64) for all 64 rows (2x2 of 32x32x16 frags, acc = 64 VGPR).
// As: kc-major 16B chunks, chunk(kc,r) at unit kc*64 + (r^(kc&7)).
// Bs: kc-major, chunk(kcl,col) at unit kcl*512 + col == Wpk order; each
// wave stages and reads only cols [wave*64, +64) -> wave-private.
__global__ __launch_bounds__(512, 1) void ffm_fused(const float* __restrict__ X,
                                                    const unsigned short* __restrict__ Wpk,
                                                    const float* __restrict__ w1,
                                                    const float* __restrict__ bvec,
                                                    float* __restrict__ out) {
    __shared__ __align__(16) unsigned short As[BM * N_FEAT];      // 64 KB
    __shared__ __align__(16) unsigned short Bs[2][N_FEAT * BKS];  // 2 x 32 KB
    __shared__ float part[8 * BM];                                // 2 KB

    const int tid  = threadIdx.x;
    const int lane = tid & 63;
    const int wave = tid >> 6;      // 0..7
    const int half = lane >> 5;     // 0/1
    const int l31  = lane & 31;

    const size_t row0 = (size_t)blockIdx.x * BM;

    // Stage step-s tile into Bs[s&1]: 4 x 16B per thread, contiguous 1KB per
    // wave-instr, dst wave-uniform + lane*16. Wave-private column span.
    auto stage = [&](int s) {
        unsigned short* dst = (unsigned short*)Bs[s & 1];
#pragma unroll
        for (int i = 0; i < 4; ++i) {
            const int ul = i * 512 + wave * 64 + lane;                 // unit in tile
            async_copy16(Wpk + ((size_t)s * 2048 + ul) * 8, dst + (size_t)ul * 8);
        }
    };

    // ---- Prologue: issue tiles 0,1 staging, build As under them ----
    stage(0);
    stage(1);
    {
        const float4* X4 = (const float4*)(X + row0 * N_FEAT);
#pragma unroll
        for (int u = 0; u < 8; ++u) {
            const int g  = u * 512 + tid;
            const int r  = g >> 6;      // wave-uniform row 0..63
            const int kc = g & 63;      // = lane: 16B chunk in row
            float4 f0 = X4[r * 128 + kc * 2];
            float4 f1 = X4[r * 128 + kc * 2 + 1];
            union { unsigned short us[8]; short8 v; } pk;
            pk.us[0] = bf16_rne(f0.x);
            pk.us[1] = bf16_rne(f0.y);
            pk.us[2] = bf16_rne(f0.z);
            pk.us[3] = bf16_rne(f0.w);
            pk.us[4] = bf16_rne(f1.x);
            pk.us[5] = bf16_rne(f1.y);
            pk.us[6] = bf16_rne(f1.z);
            pk.us[7] = bf16_rne(f1.w);
            *(short8*)(As + ((size_t)kc * 64 + (r ^ (kc & 7))) * 8) = pk.v;
        }
    }
    asm volatile("s_waitcnt lgkmcnt(0)" ::: "memory");
    __builtin_amdgcn_s_barrier();          // As visible to all waves (only barrier pre-epilogue)

    f32x16 acc[2][2];
#pragma unroll
    for (int mi = 0; mi < 2; ++mi)
#pragma unroll
        for (int ci = 0; ci < 2; ++ci)
#pragma unroll
            for (int r = 0; r < 16; ++r) acc[mi][ci][r] = 0.f;

    // Register frag double-state: [buf][si][mi/ci]
    short8 fa[2][2][2], fb[2][2][2];

    // Prefetch frags(0): tile 0 resident after vmcnt(4) (stages 0,1 = 8 out).
    asm volatile("s_waitcnt vmcnt(4)" ::: "memory");
#pragma unroll
    for (int si = 0; si < 2; ++si) {
        const int kcg = si * 2 + half;
        const int ksw = kcg & 7;
#pragma unroll
        for (int mi = 0; mi < 2; ++mi)
            fa[0][si][mi] = *(const short8*)(As + ((size_t)kcg * 64 + ((mi * 32 + l31) ^ ksw)) * 8);
#pragma unroll
        for (int ci = 0; ci < 2; ++ci)
            fb[0][si][ci] = *(const short8*)((const unsigned short*)Bs[0] +
                            ((size_t)(si * 2 + half) * 512 + wave * 64 + ci * 32 + l31) * 8);
    }

#pragma unroll
    for (int t = 0; t < NSTEP; ++t) {
        const int cur = t & 1;
        const int nxt = cur ^ 1;

        // 1) frags(t) reads complete (MFMA inputs ready; Bs[cur] WAR-safe).
        asm volatile("s_waitcnt lgkmcnt(0)" ::: "memory");
        __builtin_amdgcn_sched_barrier(0);

        // 2) stage tile t+2 into Bs[cur] (the buffer frags(t) came from).
        if (t + 2 < NSTEP) stage(t + 2);

        // 3) tile t+1 resident; prefetch frags(t+1).
        if (t + 1 < NSTEP) {
            if (t + 2 < NSTEP)
                asm volatile("s_waitcnt vmcnt(4)" ::: "memory");  // stage(t+1) done, t+2 in flight
            else
                asm volatile("s_waitcnt vmcnt(0)" ::: "memory");
            const unsigned short* bs = (const unsigned short*)Bs[nxt];
#pragma unroll
            for (int si = 0; si < 2; ++si) {
                const int kcg = (t + 1) * 4 + si * 2 + half;
                const int ksw = kcg & 7;
#pragma unroll
                for (int mi = 0; mi < 2; ++mi)
                    fa[nxt][si][mi] = *(const short8*)(As +
                        ((size_t)kcg * 64 + ((mi * 32 + l31) ^ ksw)) * 8);
#pragma unroll
                for (int ci = 0; ci < 2; ++ci)
                    fb[nxt][si][ci] = *(const short8*)(bs +
                        ((size_t)(si * 2 + half) * 512 + wave * 64 + ci * 32 + l31) * 8);
            }
        }

        // 4) MFMA on frags(t) — overlaps frags(t+1) ds-latency + stage(t+2).
        __builtin_amdgcn_s_setprio(1);
#pragma unroll
        for (int si = 0; si < 2; ++si)
#pragma unroll
            for (int mi = 0; mi < 2; ++mi)
#pragma unroll
                for (int ci = 0; ci < 2; ++ci)
                    acc[mi][ci] = __builtin_amdgcn_mfma_f32_32x32x16_bf16(
                        fa[cur][si][mi], fb[cur][si][ci], acc[mi][ci], 0, 0, 0);
        __builtin_amdgcn_s_setprio(0);
    }

    // ---- Epilogue: rs[row] = sum_col x[row][col]*(y + w1), x-hat from As (bf16).
    // C/D 32x32 layout: col = l31 (+ci*32+wave*64), row = (reg&3)+8*(reg>>2)+4*half (+mi*32).
    float w1v[2];
#pragma unroll
    for (int ci = 0; ci < 2; ++ci) w1v[ci] = w1[wave * 64 + ci * 32 + l31];
    const float bias = bvec[0];

    float rs[2][16];
#pragma unroll
    for (int mi = 0; mi < 2; ++mi) {
#pragma unroll
        for (int reg = 0; reg < 16; ++reg) {
            const int row = mi * 32 + (reg & 3) + 8 * (reg >> 2) + 4 * half;
            float s = 0.f;
#pragma unroll
            for (int ci = 0; ci < 2; ++ci) {
                const int gc = wave * 64 + ci * 32 + l31;     // k-index 0..511
                const int kc = gc >> 3;
                const float xf = bf16_to_f(As[((size_t)kc * 64 + (row ^ (kc & 7))) * 8 + (gc & 7)]);
                s = fmaf(xf, acc[mi][ci][reg] + w1v[ci], s);
            }
            rs[mi][reg] = s;
        }
    }

    // Reduce over the 32 cols held across l31, then combine 8 waves via part[].
#pragma unroll
    for (int mi = 0; mi < 2; ++mi)
#pragma unroll
        for (int reg = 0; reg < 16; ++reg) {
            float r = rs[mi][reg];
#pragma unroll
            for (int off = 1; off < 32; off <<= 1)
                r += __shfl_xor(r, off, 32);
            rs[mi][reg] = r;
        }
    if (l31 == 0) {
#pragma unroll
        for (int mi = 0; mi < 2; ++mi)
#pragma unroll
            for (int reg = 0; reg < 16; ++reg) {
                const int row = mi * 32 + (reg & 3) + 8 * (reg >> 2) + 4 * half;
                part[wave * 64 + row] = rs[mi][reg];
            }
    }
    __syncthreads();

    if (tid < BM) {
        float tsum = bias;
#pragma unroll
        for (int w = 0; w < 8; ++w) tsum += part[w * 64 + tid];
        out[row0 + tid] = 1.0f / (1.0f + expf(-tsum));
    }
}

extern "C" void kernel_launch(void* const* d_in, const int* in_sizes, int n_in,
                              void* d_out, int out_size, void* d_ws, size_t ws_size,
                              hipStream_t stream) {
    const float* X   = (const float*)d_in[0];   // 32768 x 512
    const float* w1  = (const float*)d_in[1];   // 512
    const float* b   = (const float*)d_in[2];   // 1
    const float* v   = (const float*)d_in[3];   // 512 x 30 x 40
    const int*   f2f = (const int*)d_in[4];     // 512
    float* out = (float*)d_out;                 // 32768

    unsigned short* Wpk = (unsigned short*)d_ws;   // 512 KB scratch (chunked layout)

    build_wpk<<<dim3(2, N_FEAT), 256, 0, stream>>>(v, f2f, Wpk);
    ffm_fused<<<B_ROWS / BM, 512, 0, stream>>>(X, Wpk, w1, b, out);
}

// Round 7
// 128.171 us; speedup vs baseline: 1.2998x; 1.0310x over previous
//
#include <hip/hip_runtime.h>
#include <hip/hip_bf16.h>
#include <math.h>

// FFM: B=32768, n=512, f=30, k=40
// inter[b] = X[b]^T W X[b],  W = 0.5*(C - diag(C)), C symmetric
// out = sigmoid(X@w1 + b + inter)
//
// R12: occupancy fix via Bs deletion. Wpk's chunked layout means each wave's
// B-fragments are CONTIGUOUS in global (32 lanes x 16B = 512B/segment,
// L2-resident 512KB) -> load B direct to VGPRs; no LDS staging, no barriers,
// no manual vmcnt. LDS 133->66 KB -> 2 blocks/CU, 4 waves/SIMD (R5..R11 all
// ran 2 waves/SIMD; three different schedules all ~45-52us = latency-bound,
// occupancy was the binding constraint). Grid 512 = all blocks co-resident.
// launch_bounds(512,2) caps VGPR at 128: a-frags single-buffered (demand
// ~120). As/epilogue/build unchanged from R11 (0 bank conflicts measured).

#define N_FEAT 512
#define FK 1200
#define KDIM 40
#define B_ROWS 32768
#define BM 64
#define NSTEP 16

typedef __attribute__((ext_vector_type(8))) short short8;
typedef __attribute__((ext_vector_type(16))) float f32x16;

__device__ __forceinline__ unsigned short bf16_rne(float f) {
    union { float f; unsigned int u; } c; c.f = f;
    unsigned int u = c.u;
    u += 0x7fffu + ((u >> 16) & 1u);
    return (unsigned short)(u >> 16);
}

__device__ __forceinline__ float bf16_to_f(unsigned short h) {
    union { unsigned int u; float f; } c;
    c.u = ((unsigned int)h) << 16;
    return c.f;
}

// ---------------- Kernel 1: build Wpk (512x512 bf16, chunked layout) ----------------
// Thread (i = blockIdx.y, j = blockIdx.x*256+tid) computes C[i][j], stores
// B[j][i] (symmetry) at chunk unit (j>>3)*512 + i, elem j&7. Lanes 0-7
// (consecutive j) write one contiguous 16B unit -> merged stores.
__global__ __launch_bounds__(256) void build_wpk(const float* __restrict__ v,
                                                 const int* __restrict__ f2f,
                                                 unsigned short* __restrict__ Wpk) {
    __shared__ float a_lds[FK];          // 4.8 KB
    __shared__ float c_lds[256 * 44];    // 45 KB (pad 40->44)

    const int i   = blockIdx.y;
    const int j0  = blockIdx.x * 256;
    const int tid = threadIdx.x;
    const int fi  = f2f[i];

    for (int q = tid; q < FK; q += 256) a_lds[q] = v[(size_t)i * FK + q];
    for (int q = tid; q < 2560; q += 256) {
        const int jl = q / 10, c4 = q % 10;
        *(float4*)&c_lds[jl * 44 + c4 * 4] =
            *(const float4*)&v[(size_t)(j0 + jl) * FK + fi * KDIM + c4 * 4];
    }
    __syncthreads();

    const int j  = j0 + tid;
    const int fj = f2f[j];
    const float4* a = (const float4*)&a_lds[fj * KDIM];
    const float4* c = (const float4*)&c_lds[tid * 44];
    float acc = 0.f;
#pragma unroll
    for (int q = 0; q < KDIM / 4; ++q) {
        float4 av = a[q], cv = c[q];
        acc = fmaf(av.x, cv.x, acc);
        acc = fmaf(av.y, cv.y, acc);
        acc = fmaf(av.z, cv.z, acc);
        acc = fmaf(av.w, cv.w, acc);
    }
    const unsigned short val = (i == j) ? (unsigned short)0 : bf16_rne(0.5f * acc);
    Wpk[((size_t)(j >> 3) * 512 + i) * 8 + (j & 7)] = val;
}

// ---------------- Kernel 2: fused GEMM + quadratic-form epilogue ----------------
// grid: 512 blocks x 512 threads (8 waves), 2 blocks/CU. Wave w owns output
// cols [w*64, +64) for all 64 rows (2x2 of 32x32x16 frags, acc = 64 VGPR).
// As: kc-major 16B chunks, chunk(kc,r) at unit kc*64 + (r^(kc&7)) (0-conflict).
// B: direct global->VGPR from Wpk; lane's unit = (t*4+si*2+half)*512 +
// wave*64 + ci*32 + l31 (contiguous per 32-lane half).
__global__ __launch_bounds__(512, 2) void ffm_fused(const float* __restrict__ X,
                                                    const unsigned short* __restrict__ Wpk,
                                                    const float* __restrict__ w1,
                                                    const float* __restrict__ bvec,
                                                    float* __restrict__ out) {
    __shared__ __align__(16) unsigned short As[BM * N_FEAT];      // 64 KB
    __shared__ float part[8 * BM];                                // 2 KB

    const int tid  = threadIdx.x;
    const int lane = tid & 63;
    const int wave = tid >> 6;      // 0..7
    const int half = lane >> 5;     // 0/1
    const int l31  = lane & 31;

    const size_t row0 = (size_t)blockIdx.x * BM;

    // Per-lane B base: covers half*512 + wave*64 + l31 units; step t,si adds
    // (t*4+si*2)*512 units, ci adds ci*32 units (all compile-time per unroll).
    const unsigned short* wp = Wpk + ((size_t)half * 512 + wave * 64 + l31) * 8;

    // ---- Prologue: build As (X block, bf16, kc-major + XOR swizzle) ----
    {
        const float4* X4 = (const float4*)(X + row0 * N_FEAT);
#pragma unroll
        for (int u = 0; u < 8; ++u) {
            const int g  = u * 512 + tid;
            const int r  = g >> 6;      // wave-uniform row 0..63
            const int kc = g & 63;      // = lane: 16B chunk in row
            float4 f0 = X4[r * 128 + kc * 2];
            float4 f1 = X4[r * 128 + kc * 2 + 1];
            union { unsigned short us[8]; short8 v; } pk;
            pk.us[0] = bf16_rne(f0.x);
            pk.us[1] = bf16_rne(f0.y);
            pk.us[2] = bf16_rne(f0.z);
            pk.us[3] = bf16_rne(f0.w);
            pk.us[4] = bf16_rne(f1.x);
            pk.us[5] = bf16_rne(f1.y);
            pk.us[6] = bf16_rne(f1.z);
            pk.us[7] = bf16_rne(f1.w);
            *(short8*)(As + ((size_t)kc * 64 + (r ^ (kc & 7))) * 8) = pk.v;
        }
    }
    asm volatile("s_waitcnt lgkmcnt(0)" ::: "memory");
    __builtin_amdgcn_s_barrier();          // As visible to all waves

    f32x16 acc[2][2];
#pragma unroll
    for (int mi = 0; mi < 2; ++mi)
#pragma unroll
        for (int ci = 0; ci < 2; ++ci)
#pragma unroll
            for (int r = 0; r < 16; ++r) acc[mi][ci][r] = 0.f;

    // B-fragment register double-buffer; fully unrolled loop -> static idx.
    short8 fb[2][2][2];   // [buf][si][ci]
#pragma unroll
    for (int si = 0; si < 2; ++si)
#pragma unroll
        for (int ci = 0; ci < 2; ++ci)
            fb[0][si][ci] = *(const short8*)(wp + ((size_t)(si * 2) * 512 + ci * 32) * 8);

#pragma unroll
    for (int t = 0; t < NSTEP; ++t) {
        const int cur = t & 1;
        const int nxt = cur ^ 1;

        // Prefetch B(t+1): 4 contiguous 16B loads (compiler inserts counted vmcnt).
        if (t + 1 < NSTEP) {
#pragma unroll
            for (int si = 0; si < 2; ++si)
#pragma unroll
                for (int ci = 0; ci < 2; ++ci)
                    fb[nxt][si][ci] = *(const short8*)(wp +
                        ((size_t)((t + 1) * 4 + si * 2) * 512 + ci * 32) * 8);
        }

        // A-fragments just-in-time from As (single-buffered: VGPR budget).
        short8 a[2][2];   // [si][mi]
#pragma unroll
        for (int si = 0; si < 2; ++si) {
            const int kcg = t * 4 + si * 2 + half;
            const int ksw = kcg & 7;
#pragma unroll
            for (int mi = 0; mi < 2; ++mi)
                a[si][mi] = *(const short8*)(As +
                    ((size_t)kcg * 64 + ((mi * 32 + l31) ^ ksw)) * 8);
        }

        __builtin_amdgcn_s_setprio(1);
#pragma unroll
        for (int si = 0; si < 2; ++si)
#pragma unroll
            for (int mi = 0; mi < 2; ++mi)
#pragma unroll
                for (int ci = 0; ci < 2; ++ci)
                    acc[mi][ci] = __builtin_amdgcn_mfma_f32_32x32x16_bf16(
                        a[si][mi], fb[cur][si][ci], acc[mi][ci], 0, 0, 0);
        __builtin_amdgcn_s_setprio(0);
    }

    // ---- Epilogue: rs[row] = sum_col x[row][col]*(y + w1), x-hat from As (bf16).
    // C/D 32x32 layout: col = l31 (+ci*32+wave*64), row = (reg&3)+8*(reg>>2)+4*half (+mi*32).
    float w1v[2];
#pragma unroll
    for (int ci = 0; ci < 2; ++ci) w1v[ci] = w1[wave * 64 + ci * 32 + l31];
    const float bias = bvec[0];

    float rs[2][16];
#pragma unroll
    for (int mi = 0; mi < 2; ++mi) {
#pragma unroll
        for (int reg = 0; reg < 16; ++reg) {
            const int row = mi * 32 + (reg & 3) + 8 * (reg >> 2) + 4 * half;
            float s = 0.f;
#pragma unroll
            for (int ci = 0; ci < 2; ++ci) {
                const int gc = wave * 64 + ci * 32 + l31;     // k-index 0..511
                const int kc = gc >> 3;
                const float xf = bf16_to_f(As[((size_t)kc * 64 + (row ^ (kc & 7))) * 8 + (gc & 7)]);
                s = fmaf(xf, acc[mi][ci][reg] + w1v[ci], s);
            }
            rs[mi][reg] = s;
        }
    }

    // Reduce over the 32 cols held across l31, then combine 8 waves via part[].
#pragma unroll
    for (int mi = 0; mi < 2; ++mi)
#pragma unroll
        for (int reg = 0; reg < 16; ++reg) {
            float r = rs[mi][reg];
#pragma unroll
            for (int off = 1; off < 32; off <<= 1)
                r += __shfl_xor(r, off, 32);
            rs[mi][reg] = r;
        }
    if (l31 == 0) {
#pragma unroll
        for (int mi = 0; mi < 2; ++mi)
#pragma unroll
            for (int reg = 0; reg < 16; ++reg) {
                const int row = mi * 32 + (reg & 3) + 8 * (reg >> 2) + 4 * half;
                part[wave * 64 + row] = rs[mi][reg];
            }
    }
    __syncthreads();

    if (tid < BM) {
        float tsum = bias;
#pragma unroll
        for (int w = 0; w < 8; ++w) tsum += part[w * 64 + tid];
        out[row0 + tid] = 1.0f / (1.0f + expf(-tsum));
    }
}

extern "C" void kernel_launch(void* const* d_in, const int* in_sizes, int n_in,
                              void* d_out, int out_size, void* d_ws, size_t ws_size,
                              hipStream_t stream) {
    const float* X   = (const float*)d_in[0];   // 32768 x 512
    const float* w1  = (const float*)d_in[1];   // 512
    const float* b   = (const float*)d_in[2];   // 1
    const float* v   = (const float*)d_in[3];   // 512 x 30 x 40
    const int*   f2f = (const int*)d_in[4];     // 512
    float* out = (float*)d_out;                 // 32768

    unsigned short* Wpk = (unsigned short*)d_ws;   // 512 KB scratch (chunked layout)

    build_wpk<<<dim3(2, N_FEAT), 256, 0, stream>>>(v, f2f, Wpk);
    ffm_fused<<<B_ROWS / BM, 512, 0, stream>>>(X, Wpk, w1, b, out);
}